// Round 2
// baseline (481.547 us; speedup 1.0000x reference)
//
#include <hip/hip_runtime.h>
#include <cmath>

#define HIDC 48

// ---------------------------------------------------------------------------
// block-wide mean/var over NPIX values spread across NW waves (NW*64 threads).
// ---------------------------------------------------------------------------
template <int NW>
__device__ __forceinline__ void block_mv(float s, float s2, float* red,
                                         float cntinv, float& m, float& v)
{
#pragma unroll
    for (int off = 32; off > 0; off >>= 1) {
        s  += __shfl_down(s, off);
        s2 += __shfl_down(s2, off);
    }
    int wid  = threadIdx.x >> 6;
    int lane = threadIdx.x & 63;
    if (lane == 0) { red[wid] = s; red[16 + wid] = s2; }
    __syncthreads();
    if (threadIdx.x == 0) {
        float ts = 0.f, ts2 = 0.f;
#pragma unroll
        for (int i = 0; i < NW; ++i) { ts += red[i]; ts2 += red[16 + i]; }
        red[32] = ts; red[33] = ts2;
    }
    __syncthreads();
    float mean = red[32] * cntinv;
    m = mean;
    v = red[33] * cntinv - mean * mean;
    __syncthreads();
}

// ---------------------------------------------------------------------------
// FUSED basic block: conv3x3(48ch, SAME, zero-pad) + bias, then
//   MODE 0: inorm, prelu, inorm, +res     MODE 1: inorm, prelu
// One block per (n, co) plane  -> grid (48, N). The whole plane lives in
// registers (RPT x CPT pixels per thread), so the per-plane instance norms
// need no global round-trip. Input channels staged one at a time into a
// double-buffered padded LDS plane with register prefetch; ONE barrier per
// stage (stage s+1 writes the buffer read at s-1: every thread's s-1 reads
// precede its barrier_s arrival, writes follow barrier_s departure => safe).
// ---------------------------------------------------------------------------
template <int H, int W, int THREADS, int RPT, int CPT, int MODE>
__global__ __launch_bounds__(THREADS) void fused_cn(
    const float* __restrict__ in,    // (N, 48, H, W)
    const float* __restrict__ wgt,   // (48, 48, 3, 3)   (row co)
    const float* __restrict__ bias,  // (48)
    const float* __restrict__ aptr,  // scalar prelu slope
    const float* __restrict__ res,   // (N, 48, H, W) residual (MODE 0)
    float* __restrict__ out)         // (N, 48, H, W)
{
    constexpr int NPIX = H * W;
    constexpr int PW   = W + 2;
    constexpr int PSZ  = (H + 2) * PW;
    constexpr int LPT  = (PSZ + THREADS - 1) / THREADS;
    constexpr int TXN  = W / CPT;                 // threads per row-strip
    constexpr int NW   = THREADS / 64;
    static_assert(TXN * (H / RPT) == THREADS, "bad geometry");

    __shared__ float plane[2][PSZ];
    __shared__ float red[34];

    const int t  = threadIdx.x;
    const int co = blockIdx.x;
    const int n  = blockIdx.y;
    const int tx = t % TXN;
    const int ty = t / TXN;
    const int x0 = tx * CPT;
    const int y0 = ty * RPT;

    const float* inb = in + (size_t)n * 48 * NPIX;
    const float* wb  = wgt + (size_t)co * 48 * 9;
    const size_t obase = ((size_t)n * 48 + co) * NPIX;

    float acc[RPT][CPT];
#pragma unroll
    for (int r = 0; r < RPT; ++r)
#pragma unroll
        for (int c = 0; c < CPT; ++c) acc[r][c] = 0.f;

    // prefetch channel 0
    float pref[LPT];
#pragma unroll
    for (int k = 0; k < LPT; ++k) {
        int i = t + k * THREADS;
        float v = 0.f;
        if (i < PSZ) {
            int ly = i / PW, lx = i % PW;
            int gy = ly - 1, gx = lx - 1;
            if (gy >= 0 && gy < H && gx >= 0 && gx < W)
                v = inb[gy * W + gx];
        }
        pref[k] = v;
    }

    int buf = 0;
    for (int ci = 0; ci < 48; ++ci) {
        float cur[LPT];
#pragma unroll
        for (int k = 0; k < LPT; ++k) cur[k] = pref[k];
        if (ci + 1 < 48) {
            const float* nb = inb + (size_t)(ci + 1) * NPIX;
#pragma unroll
            for (int k = 0; k < LPT; ++k) {
                int i = t + k * THREADS;
                float v = 0.f;
                if (i < PSZ) {
                    int ly = i / PW, lx = i % PW;
                    int gy = ly - 1, gx = lx - 1;
                    if (gy >= 0 && gy < H && gx >= 0 && gx < W)
                        v = nb[gy * W + gx];
                }
                pref[k] = v;
            }
        }
#pragma unroll
        for (int k = 0; k < LPT; ++k) {
            int i = t + k * THREADS;
            if (i < PSZ) plane[buf][i] = cur[k];
        }
        __syncthreads();

        float wv[9];
#pragma unroll
        for (int k = 0; k < 9; ++k) wv[k] = wb[ci * 9 + k];

        float win[RPT + 2][CPT + 2];
#pragma unroll
        for (int r = 0; r < RPT + 2; ++r)
#pragma unroll
            for (int c = 0; c < CPT + 2; ++c)
                win[r][c] = plane[buf][(y0 + r) * PW + x0 + c];
#pragma unroll
        for (int r = 0; r < RPT; ++r)
#pragma unroll
            for (int c = 0; c < CPT; ++c) {
                float s0 = win[r][c]     * wv[0] + win[r][c + 1]     * wv[1]
                         + win[r][c + 2] * wv[2] + win[r + 1][c]     * wv[3]
                         + win[r + 1][c + 1] * wv[4] + win[r + 1][c + 2] * wv[5]
                         + win[r + 2][c]     * wv[6] + win[r + 2][c + 1] * wv[7]
                         + win[r + 2][c + 2] * wv[8];
                acc[r][c] += s0;
            }
        buf ^= 1;
    }

    const float bv = bias[co];
#pragma unroll
    for (int r = 0; r < RPT; ++r)
#pragma unroll
        for (int c = 0; c < CPT; ++c) acc[r][c] += bv;

    constexpr float cntinv = 1.f / (float)NPIX;

    // inorm #1
    {
        float s = 0.f, s2 = 0.f;
#pragma unroll
        for (int r = 0; r < RPT; ++r)
#pragma unroll
            for (int c = 0; c < CPT; ++c) { s += acc[r][c]; s2 += acc[r][c] * acc[r][c]; }
        float m, v;
        block_mv<NW>(s, s2, red, cntinv, m, v);
        float rr = rsqrtf(v + 1e-5f);
#pragma unroll
        for (int r = 0; r < RPT; ++r)
#pragma unroll
            for (int c = 0; c < CPT; ++c) acc[r][c] = (acc[r][c] - m) * rr;
    }

    // prelu
    const float a = aptr[0];
#pragma unroll
    for (int r = 0; r < RPT; ++r)
#pragma unroll
        for (int c = 0; c < CPT; ++c)
            acc[r][c] = acc[r][c] >= 0.f ? acc[r][c] : a * acc[r][c];

    if (MODE == 0) {
        // inorm #2 + residual
        float s = 0.f, s2 = 0.f;
#pragma unroll
        for (int r = 0; r < RPT; ++r)
#pragma unroll
            for (int c = 0; c < CPT; ++c) { s += acc[r][c]; s2 += acc[r][c] * acc[r][c]; }
        float m, v;
        block_mv<NW>(s, s2, red, cntinv, m, v);
        float rr = rsqrtf(v + 1e-5f);
#pragma unroll
        for (int r = 0; r < RPT; ++r) {
            const float* rp = res + obase + (y0 + r) * W + x0;
#pragma unroll
            for (int c = 0; c < CPT; ++c)
                acc[r][c] = (acc[r][c] - m) * rr + rp[c];
        }
    }

#pragma unroll
    for (int r = 0; r < RPT; ++r) {
        float* op = out + obase + (y0 + r) * W + x0;
        if (CPT == 4) {
            *(float4*)op = make_float4(acc[r][0], acc[r][1], acc[r][2], acc[r][3]);
        } else if (CPT == 2) {
            *(float2*)op = make_float2(acc[r][0], acc[r][1]);
        } else {
#pragma unroll
            for (int c = 0; c < CPT; ++c) op[c] = acc[r][c];
        }
    }
}

// ---------------------------------------------------------------------------
// Pure conv3x3(SAME, zero-pad) + bias  (kept for the tiny 9-cout head).
// ---------------------------------------------------------------------------
template <int H, int W, int ROWS, int COG, int CPS, int PXT>
__global__ __launch_bounds__(256) void conv_tile(
    const float* __restrict__ in,    // (N, 48, H, W)
    const float* __restrict__ wgt,   // (COUT, 48, 3, 3)
    const float* __restrict__ bias,  // (COUT)
    float* __restrict__ out)         // (N, COUT, H, W)
{
    constexpr int NPIX = H * W;
    constexpr int PW   = W + 2;
    constexpr int CHSZ = (ROWS + 2) * PW;
    constexpr int LSZ  = CPS * CHSZ;
    constexpr int TXN  = W / PXT;          // threads per row
    constexpr int NS   = 48 / CPS;
    constexpr int LPT  = (LSZ + 255) / 256;

    static_assert(ROWS * TXN == 256, "block must be 256 threads");

    __shared__ float plane[2][LSZ];

    const int t    = threadIdx.x;
    const int cg   = blockIdx.x;
    const int rt   = blockIdx.y;
    const int n    = blockIdx.z;
    const int COUT = gridDim.x * COG;
    const int co0  = cg * COG;
    const int tx   = t % TXN;
    const int ty   = t / TXN;              // row within tile
    const int x0   = tx * PXT;
    const int r0   = rt * ROWS;

    float acc[COG][PXT];
#pragma unroll
    for (int co = 0; co < COG; ++co)
#pragma unroll
        for (int p = 0; p < PXT; ++p) acc[co][p] = 0.f;

    const float* inb = in + (size_t)n * 48 * NPIX;

    // prefetch stage 0
    float pref[LPT];
#pragma unroll
    for (int k = 0; k < LPT; ++k) {
        int i = t + k * 256;
        float v = 0.f;
        if (i < LSZ) {
            int ch  = i / CHSZ;
            int rem = i % CHSZ;
            int ly  = rem / PW, lx = rem % PW;
            int gy  = r0 + ly - 1, gx = lx - 1;
            if (gy >= 0 && gy < H && gx >= 0 && gx < W)
                v = inb[(size_t)ch * NPIX + gy * W + gx];
        }
        pref[k] = v;
    }

    int buf = 0;
    for (int s = 0; s < NS; ++s) {
        float cur[LPT];
#pragma unroll
        for (int k = 0; k < LPT; ++k) cur[k] = pref[k];
        if (s + 1 < NS) {
            const float* nb = inb + (size_t)(s + 1) * CPS * NPIX;
#pragma unroll
            for (int k = 0; k < LPT; ++k) {
                int i = t + k * 256;
                float v = 0.f;
                if (i < LSZ) {
                    int ch  = i / CHSZ;
                    int rem = i % CHSZ;
                    int ly  = rem / PW, lx = rem % PW;
                    int gy  = r0 + ly - 1, gx = lx - 1;
                    if (gy >= 0 && gy < H && gx >= 0 && gx < W)
                        v = nb[(size_t)ch * NPIX + gy * W + gx];
                }
                pref[k] = v;
            }
        }
#pragma unroll
        for (int k = 0; k < LPT; ++k) {
            int i = t + k * 256;
            if (i < LSZ) plane[buf][i] = cur[k];
        }
        __syncthreads();

#pragma unroll
        for (int c = 0; c < CPS; ++c) {
            const float* P = &plane[buf][c * CHSZ];
            float wv[COG][9];
#pragma unroll
            for (int co = 0; co < COG; ++co)
#pragma unroll
                for (int k = 0; k < 9; ++k)
                    wv[co][k] = wgt[((size_t)(co0 + co) * 48 + s * CPS + c) * 9 + k];
            float vr[3][PXT + 2];
#pragma unroll
            for (int r = 0; r < 3; ++r)
#pragma unroll
                for (int j = 0; j < PXT + 2; ++j)
                    vr[r][j] = P[(ty + r) * PW + x0 + j];
#pragma unroll
            for (int co = 0; co < COG; ++co)
#pragma unroll
                for (int p = 0; p < PXT; ++p) {
                    float s0 = vr[0][p]     * wv[co][0] + vr[0][p + 1] * wv[co][1]
                             + vr[0][p + 2] * wv[co][2] + vr[1][p]     * wv[co][3]
                             + vr[1][p + 1] * wv[co][4] + vr[1][p + 2] * wv[co][5]
                             + vr[2][p]     * wv[co][6] + vr[2][p + 1] * wv[co][7]
                             + vr[2][p + 2] * wv[co][8];
                    acc[co][p] += s0;
                }
        }
        buf ^= 1;
    }

#pragma unroll
    for (int co = 0; co < COG; ++co) {
        const float bv = bias[co0 + co];
        float* op = out + (((size_t)n * COUT + co0 + co) * H + r0 + ty) * W + x0;
#pragma unroll
        for (int p = 0; p < PXT; ++p) op[p] = acc[co][p] + bv;
    }
}

// ---------------------------------------------------------------------------
__global__ __launch_bounds__(256) void downsample4(const float* __restrict__ xin,
                                                   float* __restrict__ o)
{
    int idx = blockIdx.x * 256 + threadIdx.x;        // 786432
    int j = idx & 63;
    int i = (idx >> 6) & 63;
    int nc = idx >> 12;
    o[idx] = xin[((size_t)nc * 256 + i * 4) * 256 + j * 4];
}

// ---------------------------------------------------------------------------
__global__ __launch_bounds__(256) void maxpool2k(const float* __restrict__ a,
                                                 float* __restrict__ o)
{
    int idx = blockIdx.x * 256 + threadIdx.x;        // 196608
    int j = idx & 31;
    int i = (idx >> 5) & 31;
    int nc = idx >> 10;
    const float* p = a + ((size_t)nc * 64 + i * 2) * 64 + j * 2;
    o[idx] = fmaxf(fmaxf(p[0], p[1]), fmaxf(p[64], p[65]));
}

// ---------------------------------------------------------------------------
// Fused: bilinear 8x upsample of skernel (4,9,32,32), per-pixel softmax,
// 3x3 reflect-padded apply to x. Grid (16, 256): x = n*4+cg, y = row h.
// Halo via cross-lane shuffle; kvs p-major for conflict-free LDS.
// ---------------------------------------------------------------------------
__global__ __launch_bounds__(256) void apply_fused(const float* __restrict__ x,
                                                   const float* __restrict__ sk,
                                                   float* __restrict__ out)
{
    __shared__ float skr[9][2][32];
    __shared__ float kvs[9][256];    // p-major
    const int bx = blockIdx.x;
    const int n  = bx >> 2;
    const int cg = bx & 3;
    const int h  = blockIdx.y;
    const int t  = threadIdx.x;

    float fs = (float)h * 31.0f / 255.0f;
    int r0 = (int)fs;
    float fh = fs - (float)r0;
    int r1 = min(r0 + 1, 31);

    for (int i = t; i < 576; i += 256) {
        int p = i >> 6, rsel = (i >> 5) & 1, c = i & 31;
        int rr = rsel ? r1 : r0;
        skr[p][rsel][c] = sk[((n * 9 + p) * 32 + rr) * 32 + c];
    }
    __syncthreads();

    {
        float fcs = (float)t * 31.0f / 255.0f;
        int c0 = (int)fcs;
        float fx = fcs - (float)c0;
        int c1 = min(c0 + 1, 31);
        float kv[9];
        float mx = -1e30f;
#pragma unroll
        for (int p = 0; p < 9; ++p) {
            float v0 = skr[p][0][c0] * (1.f - fx) + skr[p][0][c1] * fx;
            float v1 = skr[p][1][c0] * (1.f - fx) + skr[p][1][c1] * fx;
            float v  = v0 * (1.f - fh) + v1 * fh;
            kv[p] = v;
            mx = fmaxf(mx, v);
        }
        float ss = 0.f;
#pragma unroll
        for (int p = 0; p < 9; ++p) { kv[p] = __expf(kv[p] - mx); ss += kv[p]; }
        float inv = 1.f / ss;
#pragma unroll
        for (int p = 0; p < 9; ++p) kvs[p][t] = kv[p] * inv;
    }
    __syncthreads();

    const int wq = t & 63;           // lane within wave == pixel quad
    const int cl = t >> 6;           // wave id == channel subgroup
    const int w4 = wq * 4;

    float kv[4][9];
#pragma unroll
    for (int p = 0; p < 9; ++p) {
        float4 v = *(const float4*)&kvs[p][w4];
        kv[0][p] = v.x; kv[1][p] = v.y; kv[2][p] = v.z; kv[3][p] = v.w;
    }

    const int hm  = (h == 0) ? 1 : h - 1;
    const int hp  = (h == 255) ? 254 : h + 1;

    const int c0ch = cg * 12 + cl * 3;
    const float* xb = x + ((size_t)n * HIDC + c0ch) * 65536;
    float* ob = out + ((size_t)n * HIDC + c0ch) * 65536;

#pragma unroll
    for (int c = 0; c < 3; ++c) {
        const float* xp = xb + (size_t)c * 65536;
        const float* rm = xp + hm * 256;
        const float* rc = xp + h * 256;
        const float* rp = xp + hp * 256;
        float4 fm = *(const float4*)(rm + w4);
        float4 fc = *(const float4*)(rc + w4);
        float4 fp = *(const float4*)(rp + w4);
        float lm = __shfl_up(fm.w, 1);   if (wq == 0)  lm = fm.y;
        float lc = __shfl_up(fc.w, 1);   if (wq == 0)  lc = fc.y;
        float lp = __shfl_up(fp.w, 1);   if (wq == 0)  lp = fp.y;
        float rmr = __shfl_down(fm.x, 1); if (wq == 63) rmr = fm.z;
        float rcr = __shfl_down(fc.x, 1); if (wq == 63) rcr = fc.z;
        float rpr = __shfl_down(fp.x, 1); if (wq == 63) rpr = fp.z;
        float vm[6] = { lm, fm.x, fm.y, fm.z, fm.w, rmr };
        float vc[6] = { lc, fc.x, fc.y, fc.z, fc.w, rcr };
        float vp[6] = { lp, fp.x, fp.y, fp.z, fp.w, rpr };
        float4 o;
        float* op = &o.x;
#pragma unroll
        for (int j = 0; j < 4; ++j) {
            op[j] = kv[j][0] * vm[j] + kv[j][1] * vm[j + 1] + kv[j][2] * vm[j + 2]
                  + kv[j][3] * vc[j] + kv[j][4] * vc[j + 1] + kv[j][5] * vc[j + 2]
                  + kv[j][6] * vp[j] + kv[j][7] * vp[j + 1] + kv[j][8] * vp[j + 2];
        }
        *(float4*)(ob + (size_t)c * 65536 + h * 256 + w4) = o;
    }
}

extern "C" void kernel_launch(void* const* d_in, const int* in_sizes, int n_in,
                              void* d_out, int out_size, void* d_ws, size_t ws_size,
                              hipStream_t stream)
{
    const float* x       = (const float*)d_in[0];
    const float* x_      = (const float*)d_in[1];
    const float* pre1_w  = (const float*)d_in[2];
    const float* pre1_b  = (const float*)d_in[3];
    const float* pre1_a  = (const float*)d_in[4];
    const float* pre2_w  = (const float*)d_in[5];
    const float* pre2_b  = (const float*)d_in[6];
    const float* pre2_a  = (const float*)d_in[7];
    const float* prek_w1 = (const float*)d_in[8];
    const float* prek_b1 = (const float*)d_in[9];
    const float* prek_a  = (const float*)d_in[10];
    const float* prek_w2 = (const float*)d_in[11];
    const float* prek_b2 = (const float*)d_in[12];
    float* out = (float*)d_out;

    float* A   = (float*)d_ws;          // (4,48,64,64) = 786432
    float* B   = A + 786432;            // (4,48,64,64)
    float* C   = A;                     // (4,48,32,32) = 196608  (A dead by then)
    float* D   = A + 196608;            // (4,48,32,32)
    float* SK  = A + 589824;            // (4,9,32,32)

    const int W1 = 48 * 48 * 9;

    downsample4<<<3072, 256, 0, stream>>>(x_, A);

    // ---- 3 fused basic blocks @ 64x64 : one block per (n,co) plane ----
    fused_cn<64, 64, 512, 2, 4, 0><<<dim3(48, 4), 512, 0, stream>>>(A, pre1_w, pre1_b, pre1_a, A, B);
    fused_cn<64, 64, 512, 2, 4, 0><<<dim3(48, 4), 512, 0, stream>>>(B, pre1_w + W1, pre1_b + 48, pre1_a + 1, B, A);
    fused_cn<64, 64, 512, 2, 4, 0><<<dim3(48, 4), 512, 0, stream>>>(A, pre1_w + 2 * W1, pre1_b + 96, pre1_a + 2, A, B);

    maxpool2k<<<768, 256, 0, stream>>>(B, C);

    // ---- 3 fused basic blocks @ 32x32 ----
    fused_cn<32, 32, 256, 2, 2, 0><<<dim3(48, 4), 256, 0, stream>>>(C, pre2_w, pre2_b, pre2_a, C, D);
    fused_cn<32, 32, 256, 2, 2, 0><<<dim3(48, 4), 256, 0, stream>>>(D, pre2_w + W1, pre2_b + 48, pre2_a + 1, D, C);
    fused_cn<32, 32, 256, 2, 2, 0><<<dim3(48, 4), 256, 0, stream>>>(C, pre2_w + 2 * W1, pre2_b + 96, pre2_a + 2, C, D);

    // ---- kernel-prediction heads ----
    fused_cn<32, 32, 256, 2, 2, 1><<<dim3(48, 4), 256, 0, stream>>>(D, prek_w1, prek_b1, prek_a, nullptr, C);
    conv_tile<32, 32, 8, 3, 4, 1><<<dim3(3, 4, 4), 256, 0, stream>>>(C, prek_w2, prek_b2, SK);

    apply_fused<<<dim3(16, 256), 256, 0, stream>>>(x, SK, out);
}

// Round 3
// 402.879 us; speedup vs baseline: 1.1953x; 1.1953x over previous
//
#include <hip/hip_runtime.h>
#include <cmath>

#define HIDC 48

// ---------------------------------------------------------------------------
// block-wide mean/var over NPIX values spread across 16 waves (1024 threads).
// ---------------------------------------------------------------------------
__device__ __forceinline__ void block_meanvar1024(float s, float s2, float* red,
                                                  float cntinv, float& m, float& v)
{
#pragma unroll
    for (int off = 32; off > 0; off >>= 1) {
        s  += __shfl_down(s, off);
        s2 += __shfl_down(s2, off);
    }
    int wid  = threadIdx.x >> 6;   // 0..15
    int lane = threadIdx.x & 63;
    if (lane == 0) { red[wid] = s; red[16 + wid] = s2; }
    __syncthreads();
    if (threadIdx.x == 0) {
        float ts = 0.f, ts2 = 0.f;
#pragma unroll
        for (int i = 0; i < 16; ++i) { ts += red[i]; ts2 += red[16 + i]; }
        red[32] = ts; red[33] = ts2;
    }
    __syncthreads();
    float mean = red[32] * cntinv;
    m = mean;
    v = red[33] * cntinv - mean * mean;
    __syncthreads();
}

// ---------------------------------------------------------------------------
// Pure conv3x3(SAME, zero-pad) + bias.
// 256 threads; each thread computes PXT horizontally-consecutive pixels of
// one row for COG consecutive couts. Tile = ROWS x W. Grid:
// (COUT/COG, H/ROWS, N).
//  - ISTR: input is read with spatial stride ISTR (fuses the ::ISTR,::ISTR
//    downsample into the conv's staging; channel stride = NPIX*ISTR*ISTR).
//  - Stage addresses (div/mod by non-pow2) are precomputed ONCE into off[]
//    (-1 = zero pad), not recomputed per stage.
//  - PW = W+4 keeps rows 16B-aligned and (with PXT==2 float2 window loads)
//    spreads a wave's LDS reads uniformly over all 32 banks (4 words/bank
//    = conflict-free).
//  - Double-buffered LDS, ONE barrier per stage (stage s+1 writes the buffer
//    read at s-1; every thread's s-1 reads precede its barrier_s arrival,
//    writes follow barrier_s departure => safe).
// ---------------------------------------------------------------------------
template <int H, int W, int ROWS, int COG, int CPS, int PXT, int ISTR>
__global__ __launch_bounds__(256) void conv_tile(
    const float* __restrict__ in,    // (N, 48, H*ISTR, W*ISTR)
    const float* __restrict__ wgt,   // (COUT, 48, 3, 3)
    const float* __restrict__ bias,  // (COUT)
    float* __restrict__ out)         // (N, COUT, H, W)
{
    constexpr int NPIX = H * W;
    constexpr int PW   = W + 4;
    constexpr int CHSZ = (ROWS + 2) * PW;
    constexpr int LSZ  = CPS * CHSZ;
    constexpr int TXN  = W / PXT;          // threads per row
    constexpr int NS   = 48 / CPS;
    constexpr int LPT  = (LSZ + 255) / 256;
    constexpr int CHST = NPIX * ISTR * ISTR;   // input channel stride
    constexpr int IW   = W * ISTR;             // input row stride

    static_assert(ROWS * TXN == 256, "block must be 256 threads");

    __shared__ float plane[2][LSZ];

    const int t    = threadIdx.x;
    const int cg   = blockIdx.x;
    const int rt   = blockIdx.y;
    const int n    = blockIdx.z;
    const int COUT = gridDim.x * COG;
    const int co0  = cg * COG;
    const int tx   = t % TXN;
    const int ty   = t / TXN;              // row within tile
    const int x0   = tx * PXT;
    const int r0   = rt * ROWS;

    float acc[COG][PXT];
#pragma unroll
    for (int co = 0; co < COG; ++co)
#pragma unroll
        for (int p = 0; p < PXT; ++p) acc[co][p] = 0.f;

    const float* inb = in + (size_t)n * 48 * CHST;

    // precompute staging offsets (loop-invariant across stages)
    int off[LPT];
#pragma unroll
    for (int k = 0; k < LPT; ++k) {
        int i = t + k * 256;
        off[k] = -1;
        if (i < LSZ) {
            int ch  = i / CHSZ;
            int rem = i % CHSZ;
            int ly  = rem / PW, lx = rem % PW;
            int gy  = r0 + ly - 1, gx = lx - 1;
            if (gy >= 0 && gy < H && gx >= 0 && gx < W)
                off[k] = ch * CHST + gy * ISTR * IW + gx * ISTR;
        }
    }

    // prefetch stage 0
    float pref[LPT];
#pragma unroll
    for (int k = 0; k < LPT; ++k)
        pref[k] = (off[k] >= 0) ? inb[off[k]] : 0.f;

    int buf = 0;
    for (int s = 0; s < NS; ++s) {
        float cur[LPT];
#pragma unroll
        for (int k = 0; k < LPT; ++k) cur[k] = pref[k];
        if (s + 1 < NS) {
            const float* nb = inb + (size_t)(s + 1) * CPS * CHST;
#pragma unroll
            for (int k = 0; k < LPT; ++k)
                pref[k] = (off[k] >= 0) ? nb[off[k]] : 0.f;
        }
#pragma unroll
        for (int k = 0; k < LPT; ++k) {
            int i = t + k * 256;
            if (i < LSZ) plane[buf][i] = cur[k];
        }
        __syncthreads();

#pragma unroll
        for (int c = 0; c < CPS; ++c) {
            const float* P = &plane[buf][c * CHSZ];
            float wv[COG][9];
#pragma unroll
            for (int co = 0; co < COG; ++co)
#pragma unroll
                for (int k = 0; k < 9; ++k)
                    wv[co][k] = wgt[((size_t)(co0 + co) * 48 + s * CPS + c) * 9 + k];
            // window rows ty..ty+2, cols x0..x0+PXT+1
            float vr[3][PXT + 2];
            if constexpr (PXT == 2) {
#pragma unroll
                for (int r = 0; r < 3; ++r) {
                    float2 a = *(const float2*)(P + (ty + r) * PW + x0);
                    float2 b = *(const float2*)(P + (ty + r) * PW + x0 + 2);
                    vr[r][0] = a.x; vr[r][1] = a.y; vr[r][2] = b.x; vr[r][3] = b.y;
                }
            } else {
#pragma unroll
                for (int r = 0; r < 3; ++r)
#pragma unroll
                    for (int j = 0; j < PXT + 2; ++j)
                        vr[r][j] = P[(ty + r) * PW + x0 + j];
            }
#pragma unroll
            for (int co = 0; co < COG; ++co)
#pragma unroll
                for (int p = 0; p < PXT; ++p) {
                    float s0 = vr[0][p]     * wv[co][0] + vr[0][p + 1] * wv[co][1]
                             + vr[0][p + 2] * wv[co][2] + vr[1][p]     * wv[co][3]
                             + vr[1][p + 1] * wv[co][4] + vr[1][p + 2] * wv[co][5]
                             + vr[2][p]     * wv[co][6] + vr[2][p + 1] * wv[co][7]
                             + vr[2][p + 2] * wv[co][8];
                    acc[co][p] += s0;
                }
        }
        buf ^= 1;
    }

#pragma unroll
    for (int co = 0; co < COG; ++co) {
        const float bv = bias[co0 + co];
        float* op = out + (((size_t)n * COUT + co0 + co) * H + r0 + ty) * W + x0;
        if (PXT == 2) {
            *(float2*)op = make_float2(acc[co][0] + bv, acc[co][PXT - 1] + bv);
        } else {
#pragma unroll
            for (int p = 0; p < PXT; ++p) op[p] = acc[co][p] + bv;
        }
    }
}

// ---------------------------------------------------------------------------
// Per-plane epilogue: inorm, prelu [, inorm, +residual].
//   MODE 0: inorm, prelu, inorm, +res   MODE 1: inorm, prelu
//   RSTR : residual is read with spatial stride RSTR from a (.,.,W*RSTR,
//          W*RSTR) tensor (fuses the downsample for block 1's residual).
// ---------------------------------------------------------------------------
template <int NPIX, int MODE, int RSTR>
__global__ __launch_bounds__(1024) void norm_block(
    const float* __restrict__ conv,
    const float* __restrict__ res,
    const float* __restrict__ aptr,
    float* __restrict__ out)
{
    constexpr int TY = NPIX / 1024;
    __shared__ float red[34];
    const int t  = threadIdx.x;
    const int co = blockIdx.x;
    const int n  = blockIdx.y;
    const size_t base = ((size_t)n * 48 + co) * NPIX;
    constexpr float cntinv = 1.f / (float)NPIX;

    float acc[TY];
#pragma unroll
    for (int r = 0; r < TY; ++r) acc[r] = conv[base + t + r * 1024];

    {
        float s = 0.f, s2 = 0.f;
#pragma unroll
        for (int r = 0; r < TY; ++r) { s += acc[r]; s2 += acc[r] * acc[r]; }
        float m, v;
        block_meanvar1024(s, s2, red, cntinv, m, v);
        float rr = rsqrtf(v + 1e-5f);
#pragma unroll
        for (int r = 0; r < TY; ++r) acc[r] = (acc[r] - m) * rr;
    }

    const float a = aptr[0];
#pragma unroll
    for (int r = 0; r < TY; ++r) acc[r] = acc[r] >= 0.f ? acc[r] : a * acc[r];

    if (MODE == 0) {
        float s = 0.f, s2 = 0.f;
#pragma unroll
        for (int r = 0; r < TY; ++r) { s += acc[r]; s2 += acc[r] * acc[r]; }
        float m, v;
        block_meanvar1024(s, s2, red, cntinv, m, v);
        float rr = rsqrtf(v + 1e-5f);
#pragma unroll
        for (int r = 0; r < TY; ++r) {
            float rv;
            if constexpr (RSTR == 1) {
                rv = res[base + t + r * 1024];
            } else {
                // NPIX=4096 (64x64), source is 256x256, stride 4
                int e = t + r * 1024;
                int i = e >> 6, j = e & 63;
                rv = res[(((size_t)n * 48 + co) << 16) + (i << 10) + (j << 2)];
            }
            acc[r] = (acc[r] - m) * rr + rv;
        }
    }

#pragma unroll
    for (int r = 0; r < TY; ++r) out[base + t + r * 1024] = acc[r];
}

// ---------------------------------------------------------------------------
__global__ __launch_bounds__(256) void maxpool2k(const float* __restrict__ a,
                                                 float* __restrict__ o)
{
    int idx = blockIdx.x * 256 + threadIdx.x;        // 196608
    int j = idx & 31;
    int i = (idx >> 5) & 31;
    int nc = idx >> 10;
    const float* p = a + ((size_t)nc * 64 + i * 2) * 64 + j * 2;
    o[idx] = fmaxf(fmaxf(p[0], p[1]), fmaxf(p[64], p[65]));
}

// ---------------------------------------------------------------------------
// Fused: bilinear 8x upsample of skernel (4,9,32,32), per-pixel softmax,
// 3x3 reflect-padded apply to x. Grid (16, 256): x = n*4+cg, y = row h.
// Halo via cross-lane shuffle; kvs p-major for conflict-free LDS; all 9
// global float4 loads hoisted ahead of the shuffle/FMA chain for MLP.
// ---------------------------------------------------------------------------
__global__ __launch_bounds__(256) void apply_fused(const float* __restrict__ x,
                                                   const float* __restrict__ sk,
                                                   float* __restrict__ out)
{
    __shared__ float skr[9][2][32];
    __shared__ float kvs[9][256];    // p-major
    const int bx = blockIdx.x;
    const int n  = bx >> 2;
    const int cg = bx & 3;
    const int h  = blockIdx.y;
    const int t  = threadIdx.x;

    float fs = (float)h * 31.0f / 255.0f;
    int r0 = (int)fs;
    float fh = fs - (float)r0;
    int r1 = min(r0 + 1, 31);

    for (int i = t; i < 576; i += 256) {
        int p = i >> 6, rsel = (i >> 5) & 1, c = i & 31;
        int rr = rsel ? r1 : r0;
        skr[p][rsel][c] = sk[((n * 9 + p) * 32 + rr) * 32 + c];
    }
    __syncthreads();

    {
        float fcs = (float)t * 31.0f / 255.0f;
        int c0 = (int)fcs;
        float fx = fcs - (float)c0;
        int c1 = min(c0 + 1, 31);
        float kv[9];
        float mx = -1e30f;
#pragma unroll
        for (int p = 0; p < 9; ++p) {
            float v0 = skr[p][0][c0] * (1.f - fx) + skr[p][0][c1] * fx;
            float v1 = skr[p][1][c0] * (1.f - fx) + skr[p][1][c1] * fx;
            float v  = v0 * (1.f - fh) + v1 * fh;
            kv[p] = v;
            mx = fmaxf(mx, v);
        }
        float ss = 0.f;
#pragma unroll
        for (int p = 0; p < 9; ++p) { kv[p] = __expf(kv[p] - mx); ss += kv[p]; }
        float inv = 1.f / ss;
#pragma unroll
        for (int p = 0; p < 9; ++p) kvs[p][t] = kv[p] * inv;
    }
    __syncthreads();

    const int wq = t & 63;           // lane within wave == pixel quad
    const int cl = t >> 6;           // wave id == channel subgroup
    const int w4 = wq * 4;

    float kv[4][9];
#pragma unroll
    for (int p = 0; p < 9; ++p) {
        float4 v = *(const float4*)&kvs[p][w4];
        kv[0][p] = v.x; kv[1][p] = v.y; kv[2][p] = v.z; kv[3][p] = v.w;
    }

    const int hm  = (h == 0) ? 1 : h - 1;
    const int hp  = (h == 255) ? 254 : h + 1;

    const int c0ch = cg * 12 + cl * 3;
    const float* xb = x + ((size_t)n * HIDC + c0ch) * 65536;
    float* ob = out + ((size_t)n * HIDC + c0ch) * 65536;

    // hoist all 9 loads (3 channels x 3 rows) before the compute chain
    float4 F[3][3];
#pragma unroll
    for (int c = 0; c < 3; ++c) {
        const float* xp = xb + (size_t)c * 65536;
        F[c][0] = *(const float4*)(xp + hm * 256 + w4);
        F[c][1] = *(const float4*)(xp + h  * 256 + w4);
        F[c][2] = *(const float4*)(xp + hp * 256 + w4);
    }

#pragma unroll
    for (int c = 0; c < 3; ++c) {
        float4 fm = F[c][0];
        float4 fc = F[c][1];
        float4 fp = F[c][2];
        float lm = __shfl_up(fm.w, 1);   if (wq == 0)  lm = fm.y;
        float lc = __shfl_up(fc.w, 1);   if (wq == 0)  lc = fc.y;
        float lp = __shfl_up(fp.w, 1);   if (wq == 0)  lp = fp.y;
        float rmr = __shfl_down(fm.x, 1); if (wq == 63) rmr = fm.z;
        float rcr = __shfl_down(fc.x, 1); if (wq == 63) rcr = fc.z;
        float rpr = __shfl_down(fp.x, 1); if (wq == 63) rpr = fp.z;
        float vm[6] = { lm, fm.x, fm.y, fm.z, fm.w, rmr };
        float vc[6] = { lc, fc.x, fc.y, fc.z, fc.w, rcr };
        float vp[6] = { lp, fp.x, fp.y, fp.z, fp.w, rpr };
        float4 o;
        float* op = &o.x;
#pragma unroll
        for (int j = 0; j < 4; ++j) {
            op[j] = kv[j][0] * vm[j] + kv[j][1] * vm[j + 1] + kv[j][2] * vm[j + 2]
                  + kv[j][3] * vc[j] + kv[j][4] * vc[j + 1] + kv[j][5] * vc[j + 2]
                  + kv[j][6] * vp[j] + kv[j][7] * vp[j + 1] + kv[j][8] * vp[j + 2];
        }
        *(float4*)(ob + (size_t)c * 65536 + h * 256 + w4) = o;
    }
}

extern "C" void kernel_launch(void* const* d_in, const int* in_sizes, int n_in,
                              void* d_out, int out_size, void* d_ws, size_t ws_size,
                              hipStream_t stream)
{
    const float* x       = (const float*)d_in[0];
    const float* x_      = (const float*)d_in[1];
    const float* pre1_w  = (const float*)d_in[2];
    const float* pre1_b  = (const float*)d_in[3];
    const float* pre1_a  = (const float*)d_in[4];
    const float* pre2_w  = (const float*)d_in[5];
    const float* pre2_b  = (const float*)d_in[6];
    const float* pre2_a  = (const float*)d_in[7];
    const float* prek_w1 = (const float*)d_in[8];
    const float* prek_b1 = (const float*)d_in[9];
    const float* prek_a  = (const float*)d_in[10];
    const float* prek_w2 = (const float*)d_in[11];
    const float* prek_b2 = (const float*)d_in[12];
    float* out = (float*)d_out;

    float* A   = (float*)d_ws;          // (4,48,64,64) = 786432
    float* B   = A + 786432;            // (4,48,64,64)
    float* RAW = B + 786432;            // (4,48,64,64) raw conv out
    float* C   = A;                     // (4,48,32,32) = 196608  (A dead by then)
    float* D   = A + 196608;            // (4,48,32,32)
    float* R2  = A + 393216;            // (4,48,32,32) raw conv out
    float* SK  = A + 589824;            // (4,9,32,32)

    const int W1 = 48 * 48 * 9;

    // ---- 3 basic blocks @ 64x64 : COG=3, conflict-free LDS, hoisted addrs.
    // Block 1 reads x_ strided (ISTR=4): downsample4 kernel eliminated;
    // its residual likewise read strided by norm_block (RSTR=4).
    conv_tile<64, 64, 8, 3, 2, 2, 4><<<dim3(16, 8, 4), 256, 0, stream>>>(x_, pre1_w, pre1_b, RAW);
    norm_block<4096, 0, 4><<<dim3(48, 4), 1024, 0, stream>>>(RAW, x_, pre1_a, B);
    conv_tile<64, 64, 8, 3, 2, 2, 1><<<dim3(16, 8, 4), 256, 0, stream>>>(B, pre1_w + W1, pre1_b + 48, RAW);
    norm_block<4096, 0, 1><<<dim3(48, 4), 1024, 0, stream>>>(RAW, B, pre1_a + 1, A);
    conv_tile<64, 64, 8, 3, 2, 2, 1><<<dim3(16, 8, 4), 256, 0, stream>>>(A, pre1_w + 2 * W1, pre1_b + 96, RAW);
    norm_block<4096, 0, 1><<<dim3(48, 4), 1024, 0, stream>>>(RAW, A, pre1_a + 2, B);

    maxpool2k<<<768, 256, 0, stream>>>(B, C);

    // ---- 3 basic blocks @ 32x32 ----
    conv_tile<32, 32, 8, 2, 4, 1, 1><<<dim3(24, 4, 4), 256, 0, stream>>>(C, pre2_w, pre2_b, R2);
    norm_block<1024, 0, 1><<<dim3(48, 4), 1024, 0, stream>>>(R2, C, pre2_a, D);
    conv_tile<32, 32, 8, 2, 4, 1, 1><<<dim3(24, 4, 4), 256, 0, stream>>>(D, pre2_w + W1, pre2_b + 48, R2);
    norm_block<1024, 0, 1><<<dim3(48, 4), 1024, 0, stream>>>(R2, D, pre2_a + 1, C);
    conv_tile<32, 32, 8, 2, 4, 1, 1><<<dim3(24, 4, 4), 256, 0, stream>>>(C, pre2_w + 2 * W1, pre2_b + 96, R2);
    norm_block<1024, 0, 1><<<dim3(48, 4), 1024, 0, stream>>>(R2, C, pre2_a + 2, D);

    // ---- kernel-prediction heads ----
    conv_tile<32, 32, 8, 2, 4, 1, 1><<<dim3(24, 4, 4), 256, 0, stream>>>(D, prek_w1, prek_b1, R2);
    norm_block<1024, 1, 1><<<dim3(48, 4), 1024, 0, stream>>>(R2, nullptr, prek_a, C);
    conv_tile<32, 32, 8, 3, 4, 1, 1><<<dim3(3, 4, 4), 256, 0, stream>>>(C, prek_w2, prek_b2, SK);

    apply_fused<<<dim3(16, 256), 256, 0, stream>>>(x, SK, out);
}

// Round 4
// 394.308 us; speedup vs baseline: 1.2212x; 1.0217x over previous
//
#include <hip/hip_runtime.h>
#include <cmath>

#define HIDC 48

// ---------------------------------------------------------------------------
// block-wide mean/var over NPIX values spread across 16 waves (1024 threads).
// ---------------------------------------------------------------------------
__device__ __forceinline__ void block_meanvar1024(float s, float s2, float* red,
                                                  float cntinv, float& m, float& v)
{
#pragma unroll
    for (int off = 32; off > 0; off >>= 1) {
        s  += __shfl_down(s, off);
        s2 += __shfl_down(s2, off);
    }
    int wid  = threadIdx.x >> 6;   // 0..15
    int lane = threadIdx.x & 63;
    if (lane == 0) { red[wid] = s; red[16 + wid] = s2; }
    __syncthreads();
    if (threadIdx.x == 0) {
        float ts = 0.f, ts2 = 0.f;
#pragma unroll
        for (int i = 0; i < 16; ++i) { ts += red[i]; ts2 += red[16 + i]; }
        red[32] = ts; red[33] = ts2;
    }
    __syncthreads();
    float mean = red[32] * cntinv;
    m = mean;
    v = red[33] * cntinv - mean * mean;
    __syncthreads();
}

// ---------------------------------------------------------------------------
// Pure conv3x3(SAME, zero-pad) + bias.
// 256 threads; each thread computes PXT horizontally-consecutive pixels of
// one row for COG consecutive couts. Tile = ROWS x W. Grid:
// (COUT/COG, H/ROWS, N).
//  - Stage addresses (div/mod by non-pow2) are precomputed ONCE into off[]
//    (-1 = zero pad), not recomputed per stage.
//  - PW = W+4 keeps rows 16B-aligned and (with PXT==2 float2 window loads)
//    spreads a wave's LDS reads uniformly over all 32 banks (2 words/bank
//    = free).
//  - Double-buffered LDS, ONE barrier per stage (stage s+1 writes the buffer
//    read at s-1; every thread's s-1 reads precede its barrier_s arrival,
//    writes follow barrier_s departure => safe).
//  NOTE (r3 lesson): do NOT fuse strided downsampling into the staging
//  reads (ISTR=4 made every block re-read the 50MB x_ with 4x cacheline
//  amplification -> 42us, FETCH=49MB). Dense input from a 3MB L2-resident
//  buffer is far cheaper; the one-time strided read lives in downsample4.
// ---------------------------------------------------------------------------
template <int H, int W, int ROWS, int COG, int CPS, int PXT>
__global__ __launch_bounds__(256) void conv_tile(
    const float* __restrict__ in,    // (N, 48, H, W)
    const float* __restrict__ wgt,   // (COUT, 48, 3, 3)
    const float* __restrict__ bias,  // (COUT)
    float* __restrict__ out)         // (N, COUT, H, W)
{
    constexpr int NPIX = H * W;
    constexpr int PW   = W + 4;
    constexpr int CHSZ = (ROWS + 2) * PW;
    constexpr int LSZ  = CPS * CHSZ;
    constexpr int TXN  = W / PXT;          // threads per row
    constexpr int NS   = 48 / CPS;
    constexpr int LPT  = (LSZ + 255) / 256;

    static_assert(ROWS * TXN == 256, "block must be 256 threads");

    __shared__ float plane[2][LSZ];

    const int t    = threadIdx.x;
    const int cg   = blockIdx.x;
    const int rt   = blockIdx.y;
    const int n    = blockIdx.z;
    const int COUT = gridDim.x * COG;
    const int co0  = cg * COG;
    const int tx   = t % TXN;
    const int ty   = t / TXN;              // row within tile
    const int x0   = tx * PXT;
    const int r0   = rt * ROWS;

    float acc[COG][PXT];
#pragma unroll
    for (int co = 0; co < COG; ++co)
#pragma unroll
        for (int p = 0; p < PXT; ++p) acc[co][p] = 0.f;

    const float* inb = in + (size_t)n * 48 * NPIX;

    // precompute staging offsets (loop-invariant across stages)
    int off[LPT];
#pragma unroll
    for (int k = 0; k < LPT; ++k) {
        int i = t + k * 256;
        off[k] = -1;
        if (i < LSZ) {
            int ch  = i / CHSZ;
            int rem = i % CHSZ;
            int ly  = rem / PW, lx = rem % PW;
            int gy  = r0 + ly - 1, gx = lx - 1;
            if (gy >= 0 && gy < H && gx >= 0 && gx < W)
                off[k] = ch * NPIX + gy * W + gx;
        }
    }

    // prefetch stage 0
    float pref[LPT];
#pragma unroll
    for (int k = 0; k < LPT; ++k)
        pref[k] = (off[k] >= 0) ? inb[off[k]] : 0.f;

    int buf = 0;
    for (int s = 0; s < NS; ++s) {
        float cur[LPT];
#pragma unroll
        for (int k = 0; k < LPT; ++k) cur[k] = pref[k];
        if (s + 1 < NS) {
            const float* nb = inb + (size_t)(s + 1) * CPS * NPIX;
#pragma unroll
            for (int k = 0; k < LPT; ++k)
                pref[k] = (off[k] >= 0) ? nb[off[k]] : 0.f;
        }
#pragma unroll
        for (int k = 0; k < LPT; ++k) {
            int i = t + k * 256;
            if (i < LSZ) plane[buf][i] = cur[k];
        }
        __syncthreads();

#pragma unroll
        for (int c = 0; c < CPS; ++c) {
            const float* P = &plane[buf][c * CHSZ];
            float wv[COG][9];
#pragma unroll
            for (int co = 0; co < COG; ++co)
#pragma unroll
                for (int k = 0; k < 9; ++k)
                    wv[co][k] = wgt[((size_t)(co0 + co) * 48 + s * CPS + c) * 9 + k];
            // window rows ty..ty+2, cols x0..x0+PXT+1
            float vr[3][PXT + 2];
            if constexpr (PXT == 2) {
#pragma unroll
                for (int r = 0; r < 3; ++r) {
                    float2 a = *(const float2*)(P + (ty + r) * PW + x0);
                    float2 b = *(const float2*)(P + (ty + r) * PW + x0 + 2);
                    vr[r][0] = a.x; vr[r][1] = a.y; vr[r][2] = b.x; vr[r][3] = b.y;
                }
            } else {
#pragma unroll
                for (int r = 0; r < 3; ++r)
#pragma unroll
                    for (int j = 0; j < PXT + 2; ++j)
                        vr[r][j] = P[(ty + r) * PW + x0 + j];
            }
#pragma unroll
            for (int co = 0; co < COG; ++co)
#pragma unroll
                for (int p = 0; p < PXT; ++p) {
                    float s0 = vr[0][p]     * wv[co][0] + vr[0][p + 1] * wv[co][1]
                             + vr[0][p + 2] * wv[co][2] + vr[1][p]     * wv[co][3]
                             + vr[1][p + 1] * wv[co][4] + vr[1][p + 2] * wv[co][5]
                             + vr[2][p]     * wv[co][6] + vr[2][p + 1] * wv[co][7]
                             + vr[2][p + 2] * wv[co][8];
                    acc[co][p] += s0;
                }
        }
        buf ^= 1;
    }

#pragma unroll
    for (int co = 0; co < COG; ++co) {
        const float bv = bias[co0 + co];
        float* op = out + (((size_t)n * COUT + co0 + co) * H + r0 + ty) * W + x0;
        if (PXT == 2) {
            *(float2*)op = make_float2(acc[co][0] + bv, acc[co][PXT - 1] + bv);
        } else {
#pragma unroll
            for (int p = 0; p < PXT; ++p) op[p] = acc[co][p] + bv;
        }
    }
}

// ---------------------------------------------------------------------------
// Per-plane epilogue: inorm, prelu [, inorm, +residual].
//   MODE 0: inorm, prelu, inorm, +res   MODE 1: inorm, prelu
// ---------------------------------------------------------------------------
template <int NPIX, int MODE>
__global__ __launch_bounds__(1024) void norm_block(
    const float* __restrict__ conv,
    const float* __restrict__ res,
    const float* __restrict__ aptr,
    float* __restrict__ out)
{
    constexpr int TY = NPIX / 1024;
    __shared__ float red[34];
    const int t  = threadIdx.x;
    const int co = blockIdx.x;
    const int n  = blockIdx.y;
    const size_t base = ((size_t)n * 48 + co) * NPIX;
    constexpr float cntinv = 1.f / (float)NPIX;

    float acc[TY];
#pragma unroll
    for (int r = 0; r < TY; ++r) acc[r] = conv[base + t + r * 1024];

    {
        float s = 0.f, s2 = 0.f;
#pragma unroll
        for (int r = 0; r < TY; ++r) { s += acc[r]; s2 += acc[r] * acc[r]; }
        float m, v;
        block_meanvar1024(s, s2, red, cntinv, m, v);
        float rr = rsqrtf(v + 1e-5f);
#pragma unroll
        for (int r = 0; r < TY; ++r) acc[r] = (acc[r] - m) * rr;
    }

    const float a = aptr[0];
#pragma unroll
    for (int r = 0; r < TY; ++r) acc[r] = acc[r] >= 0.f ? acc[r] : a * acc[r];

    if (MODE == 0) {
        float s = 0.f, s2 = 0.f;
#pragma unroll
        for (int r = 0; r < TY; ++r) { s += acc[r]; s2 += acc[r] * acc[r]; }
        float m, v;
        block_meanvar1024(s, s2, red, cntinv, m, v);
        float rr = rsqrtf(v + 1e-5f);
#pragma unroll
        for (int r = 0; r < TY; ++r)
            acc[r] = (acc[r] - m) * rr + res[base + t + r * 1024];
    }

#pragma unroll
    for (int r = 0; r < TY; ++r) out[base + t + r * 1024] = acc[r];
}

// ---------------------------------------------------------------------------
__global__ __launch_bounds__(256) void downsample4(const float* __restrict__ xin,
                                                   float* __restrict__ o)
{
    int idx = blockIdx.x * 256 + threadIdx.x;        // 786432
    int j = idx & 63;
    int i = (idx >> 6) & 63;
    int nc = idx >> 12;
    o[idx] = xin[((size_t)nc * 256 + i * 4) * 256 + j * 4];
}

// ---------------------------------------------------------------------------
__global__ __launch_bounds__(256) void maxpool2k(const float* __restrict__ a,
                                                 float* __restrict__ o)
{
    int idx = blockIdx.x * 256 + threadIdx.x;        // 196608
    int j = idx & 31;
    int i = (idx >> 5) & 31;
    int nc = idx >> 10;
    const float* p = a + ((size_t)nc * 64 + i * 2) * 64 + j * 2;
    o[idx] = fmaxf(fmaxf(p[0], p[1]), fmaxf(p[64], p[65]));
}

// ---------------------------------------------------------------------------
// Fused: bilinear 8x upsample of skernel (4,9,32,32), per-pixel softmax,
// 3x3 reflect-padded apply to x. Grid (16, 256): x = n*4+cg, y = row h.
// Halo via cross-lane shuffle; kvs p-major for conflict-free LDS; all 9
// global float4 loads hoisted ahead of the shuffle/FMA chain for MLP.
// ---------------------------------------------------------------------------
__global__ __launch_bounds__(256) void apply_fused(const float* __restrict__ x,
                                                   const float* __restrict__ sk,
                                                   float* __restrict__ out)
{
    __shared__ float skr[9][2][32];
    __shared__ float kvs[9][256];    // p-major
    const int bx = blockIdx.x;
    const int n  = bx >> 2;
    const int cg = bx & 3;
    const int h  = blockIdx.y;
    const int t  = threadIdx.x;

    float fs = (float)h * 31.0f / 255.0f;
    int r0 = (int)fs;
    float fh = fs - (float)r0;
    int r1 = min(r0 + 1, 31);

    for (int i = t; i < 576; i += 256) {
        int p = i >> 6, rsel = (i >> 5) & 1, c = i & 31;
        int rr = rsel ? r1 : r0;
        skr[p][rsel][c] = sk[((n * 9 + p) * 32 + rr) * 32 + c];
    }
    __syncthreads();

    {
        float fcs = (float)t * 31.0f / 255.0f;
        int c0 = (int)fcs;
        float fx = fcs - (float)c0;
        int c1 = min(c0 + 1, 31);
        float kv[9];
        float mx = -1e30f;
#pragma unroll
        for (int p = 0; p < 9; ++p) {
            float v0 = skr[p][0][c0] * (1.f - fx) + skr[p][0][c1] * fx;
            float v1 = skr[p][1][c0] * (1.f - fx) + skr[p][1][c1] * fx;
            float v  = v0 * (1.f - fh) + v1 * fh;
            kv[p] = v;
            mx = fmaxf(mx, v);
        }
        float ss = 0.f;
#pragma unroll
        for (int p = 0; p < 9; ++p) { kv[p] = __expf(kv[p] - mx); ss += kv[p]; }
        float inv = 1.f / ss;
#pragma unroll
        for (int p = 0; p < 9; ++p) kvs[p][t] = kv[p] * inv;
    }
    __syncthreads();

    const int wq = t & 63;           // lane within wave == pixel quad
    const int cl = t >> 6;           // wave id == channel subgroup
    const int w4 = wq * 4;

    float kv[4][9];
#pragma unroll
    for (int p = 0; p < 9; ++p) {
        float4 v = *(const float4*)&kvs[p][w4];
        kv[0][p] = v.x; kv[1][p] = v.y; kv[2][p] = v.z; kv[3][p] = v.w;
    }

    const int hm  = (h == 0) ? 1 : h - 1;
    const int hp  = (h == 255) ? 254 : h + 1;

    const int c0ch = cg * 12 + cl * 3;
    const float* xb = x + ((size_t)n * HIDC + c0ch) * 65536;
    float* ob = out + ((size_t)n * HIDC + c0ch) * 65536;

    // hoist all 9 loads (3 channels x 3 rows) before the compute chain
    float4 F[3][3];
#pragma unroll
    for (int c = 0; c < 3; ++c) {
        const float* xp = xb + (size_t)c * 65536;
        F[c][0] = *(const float4*)(xp + hm * 256 + w4);
        F[c][1] = *(const float4*)(xp + h  * 256 + w4);
        F[c][2] = *(const float4*)(xp + hp * 256 + w4);
    }

#pragma unroll
    for (int c = 0; c < 3; ++c) {
        float4 fm = F[c][0];
        float4 fc = F[c][1];
        float4 fp = F[c][2];
        float lm = __shfl_up(fm.w, 1);   if (wq == 0)  lm = fm.y;
        float lc = __shfl_up(fc.w, 1);   if (wq == 0)  lc = fc.y;
        float lp = __shfl_up(fp.w, 1);   if (wq == 0)  lp = fp.y;
        float rmr = __shfl_down(fm.x, 1); if (wq == 63) rmr = fm.z;
        float rcr = __shfl_down(fc.x, 1); if (wq == 63) rcr = fc.z;
        float rpr = __shfl_down(fp.x, 1); if (wq == 63) rpr = fp.z;
        float vm[6] = { lm, fm.x, fm.y, fm.z, fm.w, rmr };
        float vc[6] = { lc, fc.x, fc.y, fc.z, fc.w, rcr };
        float vp[6] = { lp, fp.x, fp.y, fp.z, fp.w, rpr };
        float4 o;
        float* op = &o.x;
#pragma unroll
        for (int j = 0; j < 4; ++j) {
            op[j] = kv[j][0] * vm[j] + kv[j][1] * vm[j + 1] + kv[j][2] * vm[j + 2]
                  + kv[j][3] * vc[j] + kv[j][4] * vc[j + 1] + kv[j][5] * vc[j + 2]
                  + kv[j][6] * vp[j] + kv[j][7] * vp[j + 1] + kv[j][8] * vp[j + 2];
        }
        *(float4*)(ob + (size_t)c * 65536 + h * 256 + w4) = o;
    }
}

extern "C" void kernel_launch(void* const* d_in, const int* in_sizes, int n_in,
                              void* d_out, int out_size, void* d_ws, size_t ws_size,
                              hipStream_t stream)
{
    const float* x       = (const float*)d_in[0];
    const float* x_      = (const float*)d_in[1];
    const float* pre1_w  = (const float*)d_in[2];
    const float* pre1_b  = (const float*)d_in[3];
    const float* pre1_a  = (const float*)d_in[4];
    const float* pre2_w  = (const float*)d_in[5];
    const float* pre2_b  = (const float*)d_in[6];
    const float* pre2_a  = (const float*)d_in[7];
    const float* prek_w1 = (const float*)d_in[8];
    const float* prek_b1 = (const float*)d_in[9];
    const float* prek_a  = (const float*)d_in[10];
    const float* prek_w2 = (const float*)d_in[11];
    const float* prek_b2 = (const float*)d_in[12];
    float* out = (float*)d_out;

    float* A   = (float*)d_ws;          // (4,48,64,64) = 786432
    float* B   = A + 786432;            // (4,48,64,64)
    float* RAW = B + 786432;            // (4,48,64,64) raw conv out
    float* C   = A;                     // (4,48,32,32) = 196608  (A dead by then)
    float* D   = A + 196608;            // (4,48,32,32)
    float* R2  = A + 393216;            // (4,48,32,32) raw conv out
    float* SK  = A + 589824;            // (4,9,32,32)

    const int W1 = 48 * 48 * 9;

    downsample4<<<3072, 256, 0, stream>>>(x_, A);

    // ---- 3 basic blocks @ 64x64 : COG=3, conflict-free LDS, hoisted addrs ----
    conv_tile<64, 64, 8, 3, 2, 2><<<dim3(16, 8, 4), 256, 0, stream>>>(A, pre1_w, pre1_b, RAW);
    norm_block<4096, 0><<<dim3(48, 4), 1024, 0, stream>>>(RAW, A, pre1_a, B);
    conv_tile<64, 64, 8, 3, 2, 2><<<dim3(16, 8, 4), 256, 0, stream>>>(B, pre1_w + W1, pre1_b + 48, RAW);
    norm_block<4096, 0><<<dim3(48, 4), 1024, 0, stream>>>(RAW, B, pre1_a + 1, A);
    conv_tile<64, 64, 8, 3, 2, 2><<<dim3(16, 8, 4), 256, 0, stream>>>(A, pre1_w + 2 * W1, pre1_b + 96, RAW);
    norm_block<4096, 0><<<dim3(48, 4), 1024, 0, stream>>>(RAW, A, pre1_a + 2, B);

    maxpool2k<<<768, 256, 0, stream>>>(B, C);

    // ---- 3 basic blocks @ 32x32 ----
    conv_tile<32, 32, 8, 2, 4, 1><<<dim3(24, 4, 4), 256, 0, stream>>>(C, pre2_w, pre2_b, R2);
    norm_block<1024, 0><<<dim3(48, 4), 1024, 0, stream>>>(R2, C, pre2_a, D);
    conv_tile<32, 32, 8, 2, 4, 1><<<dim3(24, 4, 4), 256, 0, stream>>>(D, pre2_w + W1, pre2_b + 48, R2);
    norm_block<1024, 0><<<dim3(48, 4), 1024, 0, stream>>>(R2, D, pre2_a + 1, C);
    conv_tile<32, 32, 8, 2, 4, 1><<<dim3(24, 4, 4), 256, 0, stream>>>(C, pre2_w + 2 * W1, pre2_b + 96, R2);
    norm_block<1024, 0><<<dim3(48, 4), 1024, 0, stream>>>(R2, C, pre2_a + 2, D);

    // ---- kernel-prediction heads ----
    conv_tile<32, 32, 8, 2, 4, 1><<<dim3(24, 4, 4), 256, 0, stream>>>(D, prek_w1, prek_b1, R2);
    norm_block<1024, 1><<<dim3(48, 4), 1024, 0, stream>>>(R2, nullptr, prek_a, C);
    conv_tile<32, 32, 8, 3, 4, 1><<<dim3(3, 4, 4), 256, 0, stream>>>(C, prek_w2, prek_b2, SK);

    apply_fused<<<dim3(16, 256), 256, 0, stream>>>(x, SK, out);
}